// Round 1
// baseline (2346.485 us; speedup 1.0000x reference)
//
#include <hip/hip_runtime.h>

// DependencyGNN: 2-layer GCN + global mean pool.
// x[200000,768] @ W1[768,256] -> normalized gather/scatter -> +b1, relu
//   -> @ W2[256,256] -> gather/scatter -> +b2 -> mean pool over batch[200000] into [8000,256]
//
// Round 1: fp32 correctness-first baseline.
//  - CSR built per call via histogram + 2-level scan + scatter (no float atomics).
//  - GEMM: fp32, 128x128 tile, 8x8 per thread, LDS-staged (no fp32 MFMA on CDNA4).
//  - Aggregate: one wave (64 lanes) per node, float4 per lane (256 ch).
//  - Pool: one wave per graph, binary search on sorted batch.

#define N_NODES_C 200000
#define N_EDGES_C 400000
#define IN_CH_C 768
#define HID_C 256
#define NUM_GRAPHS_C 8000

// ---------------- preprocessing ----------------

__global__ void zero2_kernel(int* __restrict__ a, int* __restrict__ b, int n) {
  int i = blockIdx.x * blockDim.x + threadIdx.x;
  if (i < n) { a[i] = 0; b[i] = 0; }
}

__global__ void hist_kernel(const int* __restrict__ dst, int* __restrict__ deg, int E) {
  int e = blockIdx.x * blockDim.x + threadIdx.x;
  if (e < E) atomicAdd(&deg[dst[e]], 1);
}

__global__ void dinv_kernel(const int* __restrict__ deg, float* __restrict__ dinv, int n) {
  int i = blockIdx.x * blockDim.x + threadIdx.x;
  if (i < n) dinv[i] = rsqrtf((float)(deg[i] + 1));  // +1 self-loop
}

__global__ __launch_bounds__(256) void scan1_kernel(const int* __restrict__ deg,
                                                    int* __restrict__ offs,
                                                    int* __restrict__ bsums, int n) {
  __shared__ int s[256];
  int tid = threadIdx.x;
  int i = blockIdx.x * 256 + tid;
  int v = (i < n) ? deg[i] : 0;
  s[tid] = v;
  __syncthreads();
  for (int d = 1; d < 256; d <<= 1) {
    int t = (tid >= d) ? s[tid - d] : 0;
    __syncthreads();
    s[tid] += t;
    __syncthreads();
  }
  if (i < n) offs[i] = s[tid] - v;  // exclusive within block
  if (tid == 255) bsums[blockIdx.x] = s[255];
}

__global__ __launch_bounds__(1024) void scan2_kernel(int* __restrict__ bsums, int nb) {
  __shared__ int s[1024];
  int tid = threadIdx.x;
  int v = (tid < nb) ? bsums[tid] : 0;
  s[tid] = v;
  __syncthreads();
  for (int d = 1; d < 1024; d <<= 1) {
    int t = (tid >= d) ? s[tid - d] : 0;
    __syncthreads();
    s[tid] += t;
    __syncthreads();
  }
  if (tid < nb) bsums[tid] = s[tid] - v;  // exclusive block offsets, in place
}

__global__ void scan3_kernel(int* __restrict__ offs, const int* __restrict__ bsums, int n) {
  int i = blockIdx.x * 256 + threadIdx.x;
  if (i < n) offs[i] += bsums[blockIdx.x];
  if (i == 0) offs[n] = N_EDGES_C;  // total real edges
}

__global__ void scatter_kernel(const int* __restrict__ esrc_in, const int* __restrict__ edst_in,
                               const int* __restrict__ offs, int* __restrict__ cursor,
                               const float* __restrict__ dinv,
                               int* __restrict__ esrc, float* __restrict__ enorm, int E) {
  int e = blockIdx.x * blockDim.x + threadIdx.x;
  if (e >= E) return;
  int s = esrc_in[e], d = edst_in[e];
  int pos = offs[d] + atomicAdd(&cursor[d], 1);
  esrc[pos] = s;
  enorm[pos] = dinv[s] * dinv[d];
}

// ---------------- fp32 GEMM: C[M,N] = A[M,K] x B[K,N] ----------------
// 128x128 tile, 256 threads, 8x8 accum per thread, BK=16.

#define GT_M 128
#define GT_N 128
#define GT_K 16

__global__ __launch_bounds__(256) void gemm_kernel(const float* __restrict__ A,
                                                   const float* __restrict__ B,
                                                   float* __restrict__ C,
                                                   int M, int K, int N) {
  __shared__ float As[GT_K][GT_M + 4];  // +4 pad: transpose-store 2-way max conflict (free)
  __shared__ float Bs[GT_K][GT_N];
  int tid = threadIdx.x;
  int bn = blockIdx.x, bm = blockIdx.y;   // bn fastest: consecutive blocks share A tile in L2
  int row0 = bm * GT_M, col0 = bn * GT_N;
  int tc = tid & 15, tr = tid >> 4;

  float acc[8][8];
#pragma unroll
  for (int i = 0; i < 8; ++i)
#pragma unroll
    for (int j = 0; j < 8; ++j) acc[i][j] = 0.f;

  for (int k0 = 0; k0 < K; k0 += GT_K) {
    // A tile: 128 rows x 16 k, stored transposed As[k][m]
#pragma unroll
    for (int l = 0; l < 2; ++l) {
      int idx = tid + l * 256;      // 512 float4
      int r = idx >> 2;             // tile row
      int kk = (idx & 3) << 2;      // k within chunk
      int gr = row0 + r;
      float4 v = make_float4(0.f, 0.f, 0.f, 0.f);
      if (gr < M) v = *(const float4*)&A[(size_t)gr * K + k0 + kk];
      As[kk + 0][r] = v.x; As[kk + 1][r] = v.y; As[kk + 2][r] = v.z; As[kk + 3][r] = v.w;
    }
    // B tile: 16 k x 128 cols
#pragma unroll
    for (int l = 0; l < 2; ++l) {
      int idx = tid + l * 256;
      int kk = idx >> 5;
      int c = (idx & 31) << 2;
      *(float4*)&Bs[kk][c] = *(const float4*)&B[(size_t)(k0 + kk) * N + col0 + c];
    }
    __syncthreads();
#pragma unroll
    for (int k = 0; k < GT_K; ++k) {
      float a[8], b[8];
      *(float4*)&a[0] = *(const float4*)&As[k][tr * 8];
      *(float4*)&a[4] = *(const float4*)&As[k][tr * 8 + 4];
      *(float4*)&b[0] = *(const float4*)&Bs[k][tc * 8];
      *(float4*)&b[4] = *(const float4*)&Bs[k][tc * 8 + 4];
#pragma unroll
      for (int i = 0; i < 8; ++i)
#pragma unroll
        for (int j = 0; j < 8; ++j) acc[i][j] += a[i] * b[j];
    }
    __syncthreads();
  }
#pragma unroll
  for (int i = 0; i < 8; ++i) {
    int gr = row0 + tr * 8 + i;
    if (gr < M) {
      *(float4*)&C[(size_t)gr * N + col0 + tc * 8] =
          make_float4(acc[i][0], acc[i][1], acc[i][2], acc[i][3]);
      *(float4*)&C[(size_t)gr * N + col0 + tc * 8 + 4] =
          make_float4(acc[i][4], acc[i][5], acc[i][6], acc[i][7]);
    }
  }
}

// ---------------- normalized aggregation: one wave per node ----------------
// out[i] = dinv[i]^2 * t[i] + sum_{e: dst=i} norm_e * t[src_e] + bias  (optional relu)

__global__ __launch_bounds__(256) void aggregate_kernel(
    const float* __restrict__ t, float* __restrict__ out,
    const int* __restrict__ offs, const int* __restrict__ esrc,
    const float* __restrict__ enorm, const float* __restrict__ dinv,
    const float* __restrict__ bias, int do_relu) {
  int wid = (int)(((unsigned)blockIdx.x * blockDim.x + threadIdx.x) >> 6);
  int lane = threadIdx.x & 63;
  if (wid >= N_NODES_C) return;
  int node = wid;
  float di = dinv[node];
  float sn = di * di;
  const float4 tv = *(const float4*)&t[(size_t)node * HID_C + lane * 4];
  float4 acc = make_float4(tv.x * sn, tv.y * sn, tv.z * sn, tv.w * sn);
  int beg = offs[node], end = offs[node + 1];
  for (int p = beg; p < end; ++p) {
    int s = esrc[p];
    float w = enorm[p];
    const float4 v = *(const float4*)&t[(size_t)s * HID_C + lane * 4];
    acc.x += v.x * w; acc.y += v.y * w; acc.z += v.z * w; acc.w += v.w * w;
  }
  const float4 bv = *(const float4*)&bias[lane * 4];
  acc.x += bv.x; acc.y += bv.y; acc.z += bv.z; acc.w += bv.w;
  if (do_relu) {
    acc.x = fmaxf(acc.x, 0.f); acc.y = fmaxf(acc.y, 0.f);
    acc.z = fmaxf(acc.z, 0.f); acc.w = fmaxf(acc.w, 0.f);
  }
  *(float4*)&out[(size_t)node * HID_C + lane * 4] = acc;
}

// ---------------- mean pool: one wave per graph (batch is sorted) ----------------

__device__ __forceinline__ int lower_bound_dev(const int* __restrict__ a, int n, int key) {
  int lo = 0, hi = n;
  while (lo < hi) {
    int mid = (lo + hi) >> 1;
    if (a[mid] < key) lo = mid + 1; else hi = mid;
  }
  return lo;
}

__global__ __launch_bounds__(256) void pool_kernel(const float* __restrict__ h,
                                                   const int* __restrict__ batch,
                                                   float* __restrict__ out) {
  int wid = (int)(((unsigned)blockIdx.x * blockDim.x + threadIdx.x) >> 6);
  int lane = threadIdx.x & 63;
  if (wid >= NUM_GRAPHS_C) return;
  int g = wid;
  int lo = lower_bound_dev(batch, N_NODES_C, g);
  int hi = lower_bound_dev(batch, N_NODES_C, g + 1);
  float4 acc = make_float4(0.f, 0.f, 0.f, 0.f);
  for (int i = lo; i < hi; ++i) {
    const float4 v = *(const float4*)&h[(size_t)i * HID_C + lane * 4];
    acc.x += v.x; acc.y += v.y; acc.z += v.z; acc.w += v.w;
  }
  float inv = 1.0f / fmaxf((float)(hi - lo), 1.0f);
  acc.x *= inv; acc.y *= inv; acc.z *= inv; acc.w *= inv;
  *(float4*)&out[(size_t)g * HID_C + lane * 4] = acc;
}

// ---------------- launch ----------------

extern "C" void kernel_launch(void* const* d_in, const int* in_sizes, int n_in,
                              void* d_out, int out_size, void* d_ws, size_t ws_size,
                              hipStream_t stream) {
  (void)in_sizes; (void)n_in; (void)out_size; (void)ws_size;
  const float* x  = (const float*)d_in[0];
  const float* W1 = (const float*)d_in[1];
  const float* b1 = (const float*)d_in[2];
  const float* W2 = (const float*)d_in[3];
  const float* b2 = (const float*)d_in[4];
  const int* edge_index = (const int*)d_in[5];   // [2, E] flat, int32
  const int* batch = (const int*)d_in[6];
  const int* e_src = edge_index;
  const int* e_dst = edge_index + N_EDGES_C;
  float* out = (float*)d_out;

  // workspace layout (all 16B-aligned; total ~416 MB)
  float* t     = (float*)d_ws;                       // [N, 256] transformed feats
  float* h     = t + (size_t)N_NODES_C * HID_C;      // [N, 256] aggregated feats
  float* dinv  = h + (size_t)N_NODES_C * HID_C;      // [N]
  int*   deg   = (int*)(dinv + N_NODES_C);           // [N]
  int*   offs  = deg + N_NODES_C;                    // [N+1] (+pad)
  int*   cursor = offs + (N_NODES_C + 64);           // [N]
  int*   esrc  = cursor + N_NODES_C;                 // [E]
  float* enorm = (float*)(esrc + N_EDGES_C);         // [E]
  int*   bsums = (int*)(enorm + N_EDGES_C);          // [1024]

  const int NB = (N_NODES_C + 255) / 256;            // 782 blocks over nodes
  const int EB = (N_EDGES_C + 255) / 256;            // 1563 blocks over edges

  zero2_kernel<<<NB, 256, 0, stream>>>(deg, cursor, N_NODES_C);
  hist_kernel<<<EB, 256, 0, stream>>>(e_dst, deg, N_EDGES_C);
  scan1_kernel<<<NB, 256, 0, stream>>>(deg, offs, bsums, N_NODES_C);
  scan2_kernel<<<1, 1024, 0, stream>>>(bsums, NB);
  scan3_kernel<<<NB, 256, 0, stream>>>(offs, bsums, N_NODES_C);
  dinv_kernel<<<NB, 256, 0, stream>>>(deg, dinv, N_NODES_C);
  scatter_kernel<<<EB, 256, 0, stream>>>(e_src, e_dst, offs, cursor, dinv, esrc, enorm, N_EDGES_C);

  dim3 g1(HID_C / GT_N, (N_NODES_C + GT_M - 1) / GT_M);  // (2, 1563)
  gemm_kernel<<<g1, 256, 0, stream>>>(x, W1, t, N_NODES_C, IN_CH_C, HID_C);
  aggregate_kernel<<<(N_NODES_C * 64 + 255) / 256, 256, 0, stream>>>(
      t, h, offs, esrc, enorm, dinv, b1, 1);
  gemm_kernel<<<g1, 256, 0, stream>>>(h, W2, t, N_NODES_C, HID_C, HID_C);
  aggregate_kernel<<<(N_NODES_C * 64 + 255) / 256, 256, 0, stream>>>(
      t, h, offs, esrc, enorm, dinv, b2, 0);
  pool_kernel<<<(NUM_GRAPHS_C * 64 + 255) / 256, 256, 0, stream>>>(h, batch, out);
}

// Round 2
// 1390.388 us; speedup vs baseline: 1.6876x; 1.6876x over previous
//
#include <hip/hip_runtime.h>

// DependencyGNN: 2-layer GCN + global mean pool.
// R2: GEMMs moved to bf16 MFMA (16x16x32), fp32->bf16 conversion fused into
// LDS staging; weights pre-transposed to bf16 W^T. Aggregation/pool unchanged.

#define N_NODES_C 200000
#define N_EDGES_C 400000
#define IN_CH_C 768
#define HID_C 256
#define NUM_GRAPHS_C 8000

typedef __attribute__((ext_vector_type(8))) short short8;   // 8 bf16 = 4 VGPRs
typedef __attribute__((ext_vector_type(4))) float f32x4;    // MFMA accum

__device__ __forceinline__ unsigned short f2bf(float f) {
  union { float f; unsigned u; } v; v.f = f;
  unsigned r = v.u + 0x7FFFu + ((v.u >> 16) & 1u);  // RNE
  return (unsigned short)(r >> 16);
}

// ---------------- preprocessing ----------------

__global__ void zero2_kernel(int* __restrict__ a, int* __restrict__ b, int n) {
  int i = blockIdx.x * blockDim.x + threadIdx.x;
  if (i < n) { a[i] = 0; b[i] = 0; }
}

__global__ void hist_kernel(const int* __restrict__ dst, int* __restrict__ deg, int E) {
  int e = blockIdx.x * blockDim.x + threadIdx.x;
  if (e < E) atomicAdd(&deg[dst[e]], 1);
}

__global__ void dinv_kernel(const int* __restrict__ deg, float* __restrict__ dinv, int n) {
  int i = blockIdx.x * blockDim.x + threadIdx.x;
  if (i < n) dinv[i] = rsqrtf((float)(deg[i] + 1));  // +1 self-loop
}

__global__ __launch_bounds__(256) void scan1_kernel(const int* __restrict__ deg,
                                                    int* __restrict__ offs,
                                                    int* __restrict__ bsums, int n) {
  __shared__ int s[256];
  int tid = threadIdx.x;
  int i = blockIdx.x * 256 + tid;
  int v = (i < n) ? deg[i] : 0;
  s[tid] = v;
  __syncthreads();
  for (int d = 1; d < 256; d <<= 1) {
    int t = (tid >= d) ? s[tid - d] : 0;
    __syncthreads();
    s[tid] += t;
    __syncthreads();
  }
  if (i < n) offs[i] = s[tid] - v;
  if (tid == 255) bsums[blockIdx.x] = s[255];
}

__global__ __launch_bounds__(1024) void scan2_kernel(int* __restrict__ bsums, int nb) {
  __shared__ int s[1024];
  int tid = threadIdx.x;
  int v = (tid < nb) ? bsums[tid] : 0;
  s[tid] = v;
  __syncthreads();
  for (int d = 1; d < 1024; d <<= 1) {
    int t = (tid >= d) ? s[tid - d] : 0;
    __syncthreads();
    s[tid] += t;
    __syncthreads();
  }
  if (tid < nb) bsums[tid] = s[tid] - v;
}

__global__ void scan3_kernel(int* __restrict__ offs, const int* __restrict__ bsums, int n) {
  int i = blockIdx.x * 256 + threadIdx.x;
  if (i < n) offs[i] += bsums[blockIdx.x];
  if (i == 0) offs[n] = N_EDGES_C;
}

__global__ void scatter_kernel(const int* __restrict__ esrc_in, const int* __restrict__ edst_in,
                               const int* __restrict__ offs, int* __restrict__ cursor,
                               const float* __restrict__ dinv,
                               int* __restrict__ esrc, float* __restrict__ enorm, int E) {
  int e = blockIdx.x * blockDim.x + threadIdx.x;
  if (e >= E) return;
  int s = esrc_in[e], d = edst_in[e];
  int pos = offs[d] + atomicAdd(&cursor[d], 1);
  esrc[pos] = s;
  enorm[pos] = dinv[s] * dinv[d];
}

// ---------------- weight prep: WT[n*K+k] = bf16(W[k*N+n]) ----------------

__global__ void wprep_kernel(const float* __restrict__ W, unsigned short* __restrict__ WT,
                             int K, int N, int total) {
  int idx = blockIdx.x * blockDim.x + threadIdx.x;
  if (idx >= total) return;
  int n = idx / K, k = idx - n * K;
  WT[idx] = f2bf(W[(size_t)k * N + n]);
}

// ---------------- bf16 MFMA GEMM: C[M,256] = A[M,K] x BT[256,K]^T ----------------
// 128x128 tile, 256 threads (4 waves 2x2, each wave 64x64 = 4x4 MFMA 16x16x32).
// A fp32 converted to bf16 during staging; BT already bf16 (transposed weights).

#define BM 128
#define BN 128
#define BK 32
#define LDT 40  // BK + 8 pad (ushort units; 80 B row stride -> conflict-free frag reads)

__global__ __launch_bounds__(256) void gemm_bf16_kernel(
    const float* __restrict__ A, const unsigned short* __restrict__ BT,
    float* __restrict__ C, int M, int K) {
  __shared__ unsigned short As[BM * LDT];
  __shared__ unsigned short Bs[BN * LDT];
  const int tid = threadIdx.x;
  const int row0 = blockIdx.y * BM;
  const int col0 = blockIdx.x * BN;
  const int lane = tid & 63;
  const int w = tid >> 6;
  const int wm = (w >> 1) * 64, wn = (w & 1) * 64;
  const int r16 = lane & 15, quad = lane >> 4;

  f32x4 acc[4][4] = {};

  const int srow = tid >> 1;        // staging row 0..127
  const int sk = (tid & 1) * 16;    // k offset 0 / 16

  for (int k0 = 0; k0 < K; k0 += BK) {
    // stage A: 16 fp32 -> 16 bf16 per thread
    {
      const int gr = row0 + srow;
      float vals[16];
      if (gr < M) {
        const float* ap = &A[(size_t)gr * K + k0 + sk];
#pragma unroll
        for (int i = 0; i < 4; ++i) *(float4*)&vals[i * 4] = *(const float4*)&ap[i * 4];
      } else {
#pragma unroll
        for (int i = 0; i < 16; ++i) vals[i] = 0.f;
      }
      unsigned short hb[16];
#pragma unroll
      for (int i = 0; i < 16; ++i) hb[i] = f2bf(vals[i]);
      *(uint4*)&As[srow * LDT + sk] = *(uint4*)&hb[0];
      *(uint4*)&As[srow * LDT + sk + 8] = *(uint4*)&hb[8];
    }
    // stage B: straight bf16 copy (rows of WT are k-contiguous)
    {
      const unsigned short* bp = &BT[(size_t)(col0 + srow) * K + k0 + sk];
      uint4 v0 = *(const uint4*)&bp[0];
      uint4 v1 = *(const uint4*)&bp[8];
      *(uint4*)&Bs[srow * LDT + sk] = v0;
      *(uint4*)&Bs[srow * LDT + sk + 8] = v1;
    }
    __syncthreads();

    short8 af[4], bfr[4];
#pragma unroll
    for (int i = 0; i < 4; ++i)
      af[i] = *(const short8*)&As[(wm + i * 16 + r16) * LDT + quad * 8];
#pragma unroll
    for (int j = 0; j < 4; ++j)
      bfr[j] = *(const short8*)&Bs[(wn + j * 16 + r16) * LDT + quad * 8];
#pragma unroll
    for (int i = 0; i < 4; ++i)
#pragma unroll
      for (int j = 0; j < 4; ++j)
        acc[i][j] = __builtin_amdgcn_mfma_f32_16x16x32_bf16(af[i], bfr[j], acc[i][j], 0, 0, 0);
    __syncthreads();
  }

  // epilogue: C/D layout col=lane&15, row=quad*4+reg (m89-verified)
#pragma unroll
  for (int i = 0; i < 4; ++i) {
#pragma unroll
    for (int r = 0; r < 4; ++r) {
      int gr = row0 + wm + i * 16 + quad * 4 + r;
      if (gr < M) {
#pragma unroll
        for (int j = 0; j < 4; ++j)
          C[(size_t)gr * HID_C + col0 + wn + j * 16 + r16] = acc[i][j][r];
      }
    }
  }
}

// ---------------- normalized aggregation: one wave per node ----------------

__global__ __launch_bounds__(256) void aggregate_kernel(
    const float* __restrict__ t, float* __restrict__ out,
    const int* __restrict__ offs, const int* __restrict__ esrc,
    const float* __restrict__ enorm, const float* __restrict__ dinv,
    const float* __restrict__ bias, int do_relu) {
  int wid = (int)(((unsigned)blockIdx.x * blockDim.x + threadIdx.x) >> 6);
  int lane = threadIdx.x & 63;
  if (wid >= N_NODES_C) return;
  int node = wid;
  float di = dinv[node];
  float sn = di * di;
  const float4 tv = *(const float4*)&t[(size_t)node * HID_C + lane * 4];
  float4 acc = make_float4(tv.x * sn, tv.y * sn, tv.z * sn, tv.w * sn);
  int beg = offs[node], end = offs[node + 1];
  for (int p = beg; p < end; ++p) {
    int s = esrc[p];
    float w = enorm[p];
    const float4 v = *(const float4*)&t[(size_t)s * HID_C + lane * 4];
    acc.x += v.x * w; acc.y += v.y * w; acc.z += v.z * w; acc.w += v.w * w;
  }
  const float4 bv = *(const float4*)&bias[lane * 4];
  acc.x += bv.x; acc.y += bv.y; acc.z += bv.z; acc.w += bv.w;
  if (do_relu) {
    acc.x = fmaxf(acc.x, 0.f); acc.y = fmaxf(acc.y, 0.f);
    acc.z = fmaxf(acc.z, 0.f); acc.w = fmaxf(acc.w, 0.f);
  }
  *(float4*)&out[(size_t)node * HID_C + lane * 4] = acc;
}

// ---------------- mean pool ----------------

__device__ __forceinline__ int lower_bound_dev(const int* __restrict__ a, int n, int key) {
  int lo = 0, hi = n;
  while (lo < hi) {
    int mid = (lo + hi) >> 1;
    if (a[mid] < key) lo = mid + 1; else hi = mid;
  }
  return lo;
}

__global__ __launch_bounds__(256) void pool_kernel(const float* __restrict__ h,
                                                   const int* __restrict__ batch,
                                                   float* __restrict__ out) {
  int wid = (int)(((unsigned)blockIdx.x * blockDim.x + threadIdx.x) >> 6);
  int lane = threadIdx.x & 63;
  if (wid >= NUM_GRAPHS_C) return;
  int g = wid;
  int lo = lower_bound_dev(batch, N_NODES_C, g);
  int hi = lower_bound_dev(batch, N_NODES_C, g + 1);
  float4 acc = make_float4(0.f, 0.f, 0.f, 0.f);
  for (int i = lo; i < hi; ++i) {
    const float4 v = *(const float4*)&h[(size_t)i * HID_C + lane * 4];
    acc.x += v.x; acc.y += v.y; acc.z += v.z; acc.w += v.w;
  }
  float inv = 1.0f / fmaxf((float)(hi - lo), 1.0f);
  acc.x *= inv; acc.y *= inv; acc.z *= inv; acc.w *= inv;
  *(float4*)&out[(size_t)g * HID_C + lane * 4] = acc;
}

// ---------------- launch ----------------

extern "C" void kernel_launch(void* const* d_in, const int* in_sizes, int n_in,
                              void* d_out, int out_size, void* d_ws, size_t ws_size,
                              hipStream_t stream) {
  (void)in_sizes; (void)n_in; (void)out_size; (void)ws_size;
  const float* x  = (const float*)d_in[0];
  const float* W1 = (const float*)d_in[1];
  const float* b1 = (const float*)d_in[2];
  const float* W2 = (const float*)d_in[3];
  const float* b2 = (const float*)d_in[4];
  const int* edge_index = (const int*)d_in[5];
  const int* batch = (const int*)d_in[6];
  const int* e_src = edge_index;
  const int* e_dst = edge_index + N_EDGES_C;
  float* out = (float*)d_out;

  // workspace layout
  float* t      = (float*)d_ws;
  float* h      = t + (size_t)N_NODES_C * HID_C;
  float* dinv   = h + (size_t)N_NODES_C * HID_C;
  int*   deg    = (int*)(dinv + N_NODES_C);
  int*   offs   = deg + N_NODES_C;
  int*   cursor = offs + (N_NODES_C + 64);
  int*   esrc   = cursor + N_NODES_C;
  float* enorm  = (float*)(esrc + N_EDGES_C);
  int*   bsums  = (int*)(enorm + N_EDGES_C);
  // W1T/W2T alias the cursor region (524 KB < 800 KB): cursor is dead after
  // scatter_kernel, and wprep_* launch AFTER scatter. 16B-aligned (offset
  // 412,000,256 from ws base).
  unsigned short* W1T = (unsigned short*)cursor;
  unsigned short* W2T = W1T + (size_t)IN_CH_C * HID_C;

  const int NB = (N_NODES_C + 255) / 256;
  const int EB = (N_EDGES_C + 255) / 256;

  zero2_kernel<<<NB, 256, 0, stream>>>(deg, cursor, N_NODES_C);
  hist_kernel<<<EB, 256, 0, stream>>>(e_dst, deg, N_EDGES_C);
  scan1_kernel<<<NB, 256, 0, stream>>>(deg, offs, bsums, N_NODES_C);
  scan2_kernel<<<1, 1024, 0, stream>>>(bsums, NB);
  scan3_kernel<<<NB, 256, 0, stream>>>(offs, bsums, N_NODES_C);
  dinv_kernel<<<NB, 256, 0, stream>>>(deg, dinv, N_NODES_C);
  scatter_kernel<<<EB, 256, 0, stream>>>(e_src, e_dst, offs, cursor, dinv, esrc, enorm, N_EDGES_C);

  // weight prep (after scatter: W1T/W2T alias cursor)
  wprep_kernel<<<(IN_CH_C * HID_C + 255) / 256, 256, 0, stream>>>(W1, W1T, IN_CH_C, HID_C, IN_CH_C * HID_C);
  wprep_kernel<<<(HID_C * HID_C + 255) / 256, 256, 0, stream>>>(W2, W2T, HID_C, HID_C, HID_C * HID_C);

  dim3 g1(HID_C / BN, (N_NODES_C + BM - 1) / BM);  // (2, 1563)
  gemm_bf16_kernel<<<g1, 256, 0, stream>>>(x, W1T, t, N_NODES_C, IN_CH_C);
  aggregate_kernel<<<(N_NODES_C * 64 + 255) / 256, 256, 0, stream>>>(
      t, h, offs, esrc, enorm, dinv, b1, 1);
  gemm_bf16_kernel<<<g1, 256, 0, stream>>>(h, W2T, t, N_NODES_C, HID_C);
  aggregate_kernel<<<(N_NODES_C * 64 + 255) / 256, 256, 0, stream>>>(
      t, h, offs, esrc, enorm, dinv, b2, 0);
  pool_kernel<<<(NUM_GRAPHS_C * 64 + 255) / 256, 256, 0, stream>>>(h, batch, out);
}